// Round 4
// baseline (1081.581 us; speedup 1.0000x reference)
//
#include <hip/hip_runtime.h>
#include <math.h>

#define NF 39
#define ND 13
#define NS 26                         // sparse fields
#define KDIM 16
#define FEAT 260013
#define NPAIRS (NF * (NF + 1) / 2)    // 780 unordered pairs (i<=j)

// ---- transposed-layout path ----
#define ROWF4 4                       // float4 per (row,feature) vector
#define CHUNKF4 (NF * ROWF4)          // 156 f4 per feature chunk in WT
#define CHUNKF4_PAD 157
#define PAIR_SLOTS 832                // 13 passes * 64 pair slots (4 lanes/pair)
#define CPASSES 13
#define TFEAT 20                      // features per transpose group
#define TROWF4 (TFEAT * ROWF4)        // 80
#define TROWF4_PAD 81
#define TTHREADS 512
#define TNITER 8                      // consecutive groups per block (contiguous reads)
#define TGROUPS ((FEAT + TFEAT - 1) / TFEAT)        // 13001
#define TBLOCKS ((TGROUPS + TNITER - 1) / TNITER)   // 1626
#define BITWORDS ((FEAT + 31) / 32)
#define MAIN_BLOCKS 512
#define MTHREADS 256
#define PRE_N ((NS * CHUNKF4 + MTHREADS - 1) / MTHREADS)   // 16

__global__ __launch_bounds__(256) void ffm_clear_bits(unsigned* __restrict__ bits)
{
    int t = blockIdx.x * 256 + threadIdx.x;
    if (t < BITWORDS) bits[t] = 0u;
}

__global__ __launch_bounds__(256) void ffm_mark_bits(
    const float* __restrict__ x, const int* __restrict__ offsets,
    unsigned* __restrict__ bits, int B)
{
    int t = blockIdx.x * 256 + threadIdx.x;
    if (t >= B * NS) return;
    int b  = t / NS;
    int jj = ND + (t - b * NS);
    int f  = offsets[jj] + (int)floorf(x[(size_t)b * NF + jj]);
    atomicOr(&bits[f >> 5], 1u << (f & 31));
}

// WT[f][i][k] = W[i][f][k], written only for used features. Each block handles
// TNITER consecutive feature-groups so per-row global reads are time-contiguous
// ~10KB streams (round-1/2 read 1280B islands -> phase-serialized latency).
__global__ __launch_bounds__(TTHREADS) void ffm_transpose(
    const float4* __restrict__ W4,    // [39 * FEAT * 4] f4
    float4* __restrict__ WT4,         // [FEAT * 156] f4
    const unsigned* __restrict__ bits)
{
    __shared__ float4 sT[NF * TROWF4_PAD];   // 50,544 B -> 3 blocks/CU
    __shared__ char   sUsed[TFEAT];
    const int tid = threadIdx.x;

    for (int it = 0; it < TNITER; ++it) {
        const int g = blockIdx.x * TNITER + it;
        if (g >= TGROUPS) break;
        const int fbase  = g * TFEAT;
        const int fbase4 = fbase * 4;

        if (tid < TFEAT) {
            int f = fbase + tid;
            int u = 0;
            if (f < FEAT)
                u = (f < ND) ? 1 : (int)((bits[f >> 5] >> (f & 31)) & 1u);
            sUsed[tid] = (char)u;
        }

        #pragma unroll
        for (int r = tid; r < NF * TROWF4; r += TTHREADS) {
            int row = r / TROWF4;
            int w   = r - row * TROWF4;
            if (fbase + (w >> 2) < FEAT)
                sT[row * TROWF4_PAD + w] = W4[(size_t)row * (FEAT * 4) + fbase4 + w];
        }
        __syncthreads();

        #pragma unroll
        for (int o = tid; o < TFEAT * CHUNKF4; o += TTHREADS) {
            int fl  = o / CHUNKF4;
            int rem = o - fl * CHUNKF4;
            int f   = fbase + fl;
            if (f < FEAT && sUsed[fl])
                WT4[(size_t)f * CHUNKF4 + rem] =
                    sT[(rem >> 2) * TROWF4_PAD + (fl << 2) + (rem & 3)];
        }
        __syncthreads();   // sT/sUsed reuse next iteration
    }
}

// Software-pipelined persistent main: per sample, issue next sample's chunk
// loads into registers (T14 issue-early), compute current sample from LDS
// (hides the HBM latency), then ds_write regs->LDS after the barrier.
// Weights: static table * sxm[i]*sxm[j] in-pass (sxm sparse == 1).
// Dense chunk bases are sample-invariant (idx=0) -> constant sgbD, L1/L2-hot.
__global__ __launch_bounds__(MTHREADS) void ffm_main(
    const float* __restrict__ x,       // [B, 39]
    const float4* __restrict__ WT4,    // [FEAT * 156] f4
    const float* __restrict__ fc_w,    // [FEAT]
    const float* __restrict__ bias,    // [1]
    const int*   __restrict__ offsets, // [39]
    float* __restrict__ out,           // [B]
    int B)
{
    __shared__ float4         sC[NS * CHUNKF4_PAD];  // 65,312 B -> 2 blocks/CU
    __shared__ float          sxm[NF];
    __shared__ int            sfeat[NF];
    __shared__ int            sgbS[NS];   // sparse chunk f4-base of NEXT sample
    __shared__ int            sgbD[ND];   // dense chunk f4-base (constant)
    __shared__ unsigned short spij[PAIR_SLOTS];
    __shared__ float          swst[PAIR_SLOTS];
    __shared__ float          sred[4];

    const int tid  = threadIdx.x;
    const int slot = tid >> 2;
    const int q    = tid & 3;

    // static tables: pair (i,j) + structural weight.
    //   i==j<38: 1 ; i<j<38: 2 ; i<j==38: 1 ; (38,38): 0 ; padding: 0
    for (int p = tid; p < PAIR_SLOTS; p += MTHREADS) {
        int i = 0, j = 0; float w = 0.0f;
        if (p < NPAIRS) {
            int base = 0, ii = 0;
            while (p >= base + (NF - ii)) { base += NF - ii; ++ii; }
            i = ii; j = ii + (p - base);
            if (i == j)          w = (i < NF - 1) ? 1.0f : 0.0f;
            else if (j < NF - 1) w = 2.0f;
            else                 w = 1.0f;
        }
        spij[p] = (unsigned short)(i | (j << 8));
        swst[p] = w;
    }
    if (tid < ND) {
        sgbD[tid]  = offsets[tid] * CHUNKF4;
        sfeat[tid] = offsets[tid];
    }

    const int b0 = blockIdx.x;
    if (tid < NF) {
        float xv = x[(size_t)b0 * NF + tid];
        if (tid < ND) {
            sxm[tid] = xv;
        } else {
            int f = (int)floorf(xv) + offsets[tid];
            sfeat[tid]     = f;
            sxm[tid]       = 1.0f;
            sgbS[tid - ND] = f * CHUNKF4;
        }
    }
    __syncthreads();

    float4 pre[PRE_N];

    // prologue: stage b0 chunks
    #pragma unroll
    for (int u = 0; u < PRE_N; ++u) {
        int idx = u * MTHREADS + tid;
        if (idx < NS * CHUNKF4) {
            int c = idx / CHUNKF4;
            int w = idx - c * CHUNKF4;
            pre[u] = WT4[(size_t)sgbS[c] + w];
        }
    }
    __syncthreads();   // sgbS fully consumed
    #pragma unroll
    for (int u = 0; u < PRE_N; ++u) {
        int idx = u * MTHREADS + tid;
        if (idx < NS * CHUNKF4) {
            int c = idx / CHUNKF4;
            int w = idx - c * CHUNKF4;
            sC[c * CHUNKF4_PAD + w] = pre[u];
        }
    }
    {
        int b1 = b0 + MAIN_BLOCKS;
        if (b1 < B && tid >= ND && tid < NF) {
            float xv = x[(size_t)b1 * NF + tid];
            sgbS[tid - ND] = ((int)floorf(xv) + offsets[tid]) * CHUNKF4;
        }
    }
    __syncthreads();   // sC(b0) + sgbS(b1) ready

    for (int b = b0; b < B; b += MAIN_BLOCKS) {
        const int bn = b + MAIN_BLOCKS;

        // 1. issue next sample's chunk loads (latency hides under compute)
        if (bn < B) {
            #pragma unroll
            for (int u = 0; u < PRE_N; ++u) {
                int idx = u * MTHREADS + tid;
                if (idx < NS * CHUNKF4) {
                    int c = idx / CHUNKF4;
                    int w = idx - c * CHUNKF4;
                    pre[u] = WT4[(size_t)sgbS[c] + w];
                }
            }
        }

        // 2. compute current sample from LDS
        float acc = (tid < NF) ? fc_w[sfeat[tid]] : 0.0f;   // linear term
        #pragma unroll 4
        for (int pass = 0; pass < CPASSES; ++pass) {
            int   p   = pass * 64 + slot;
            int   ij  = spij[p];
            int   i   = ij & 0xff;
            int   j   = ij >> 8;
            float wgt = swst[p] * sxm[i] * sxm[j];

            float4 a = (j >= ND) ? sC[(j - ND) * CHUNKF4_PAD + (i << 2) + q]
                                 : WT4[(size_t)sgbD[j] + (i << 2) + q];
            float4 v = (i >= ND) ? sC[(i - ND) * CHUNKF4_PAD + (j << 2) + q]
                                 : WT4[(size_t)sgbD[i] + (j << 2) + q];

            acc += wgt * (a.x * v.x + a.y * v.y + a.z * v.z + a.w * v.w);
        }
        #pragma unroll
        for (int off = 32; off > 0; off >>= 1)
            acc += __shfl_down(acc, off, 64);
        if ((tid & 63) == 0) sred[tid >> 6] = acc;
        __syncthreads();   // A: compute done; sC/sxm/sgbS free; sred ready

        if (tid == 0) {
            float z = sred[0] + sred[1] + sred[2] + sred[3] + bias[0];
            out[b] = 1.0f / (1.0f + expf(-z));
        }

        if (bn < B) {
            // 3. write prefetched chunks into LDS (vmcnt wait lands here)
            #pragma unroll
            for (int u = 0; u < PRE_N; ++u) {
                int idx = u * MTHREADS + tid;
                if (idx < NS * CHUNKF4) {
                    int c = idx / CHUNKF4;
                    int w = idx - c * CHUNKF4;
                    sC[c * CHUNKF4_PAD + w] = pre[u];
                }
            }
            // 4. tables for bn; sgbS for bn+MAIN_BLOCKS
            if (tid < NF) {
                float xv = x[(size_t)bn * NF + tid];
                if (tid < ND) sxm[tid] = xv;
                else          sfeat[tid] = (int)floorf(xv) + offsets[tid];
            }
            int b2 = bn + MAIN_BLOCKS;
            if (b2 < B && tid >= ND && tid < NF) {
                float xv2 = x[(size_t)b2 * NF + tid];
                sgbS[tid - ND] = ((int)floorf(xv2) + offsets[tid]) * CHUNKF4;
            }
            __syncthreads();   // B: sC(bn) + tables(bn) + sgbS(b2) ready
        }
    }
}

// ---- fallback: verified round-0 kernel (native W layout, 8 lanes/pair) ----
#define PASSES ((NPAIRS + 31) / 32)
__global__ __launch_bounds__(256) void ffm_kernel(
    const float* __restrict__ x, const float* __restrict__ W,
    const float* __restrict__ fc_w, const float* __restrict__ bias,
    const int* __restrict__ offsets, float* __restrict__ out, int B)
{
    __shared__ int            sf[NF];
    __shared__ float          sxm[NF];
    __shared__ unsigned short spij[NPAIRS];
    __shared__ float          sred[4];

    const int b   = blockIdx.x;
    const int tid = threadIdx.x;

    if (tid < NF) {
        float xv = x[(size_t)b * NF + tid];
        int idx  = (tid < ND) ? 0 : (int)floorf(xv);
        sf[tid]  = idx + offsets[tid];
        sxm[tid] = (tid < ND) ? xv : 1.0f;
    }
    for (int p = tid; p < NPAIRS; p += 256) {
        int i = 0, base = 0;
        while (p >= base + (NF - i)) { base += NF - i; ++i; }
        int j = i + (p - base);
        spij[p] = (unsigned short)(i | (j << 8));
    }
    __syncthreads();

    const int slot = tid >> 3;
    const int quad = (tid >> 2) & 1;
    const int qi   = tid & 3;

    float acc = 0.0f;
    if (tid < NF) acc += fc_w[sf[tid]];

    #pragma unroll 5
    for (int pass = 0; pass < PASSES; ++pass) {
        int p  = pass * 32 + slot;
        int pc = (p < NPAIRS) ? p : (NPAIRS - 1);
        int ij = spij[pc];
        int i  = ij & 0xff;
        int j  = ij >> 8;

        float w;
        if (i == j)          w = (i < NF - 1) ? sxm[i] * sxm[i] : 0.0f;
        else if (j < NF - 1) w = 2.0f * sxm[i] * sxm[j];
        else                 w = sxm[i] * sxm[j];
        if (p >= NPAIRS) w = 0.0f;

        int row  = quad ? j : i;
        int feat = quad ? sf[i] : sf[j];
        const float4* vp = (const float4*)(W + ((size_t)row * FEAT + feat) * KDIM);
        float4 v = vp[qi];

        float4 u;
        u.x = __shfl_xor(v.x, 4, 64);
        u.y = __shfl_xor(v.y, 4, 64);
        u.z = __shfl_xor(v.z, 4, 64);
        u.w = __shfl_xor(v.w, 4, 64);

        float d = v.x * u.x + v.y * u.y + v.z * u.z + v.w * u.w;
        acc += 0.5f * w * d;
    }

    #pragma unroll
    for (int off = 32; off > 0; off >>= 1)
        acc += __shfl_down(acc, off, 64);
    if ((tid & 63) == 0) sred[tid >> 6] = acc;
    __syncthreads();

    if (tid == 0) {
        float z = sred[0] + sred[1] + sred[2] + sred[3] + bias[0];
        out[b] = 1.0f / (1.0f + expf(-z));
    }
}

extern "C" void kernel_launch(void* const* d_in, const int* in_sizes, int n_in,
                              void* d_out, int out_size, void* d_ws, size_t ws_size,
                              hipStream_t stream) {
    const float* x       = (const float*)d_in[0];
    const float* W       = (const float*)d_in[1];
    const float* fc_w    = (const float*)d_in[2];
    const float* bias    = (const float*)d_in[3];
    const int*   offsets = (const int*)d_in[4];

    float* out = (float*)d_out;
    const int B = in_sizes[0] / NF;

    const size_t WT_BYTES  = (size_t)FEAT * NF * KDIM * sizeof(float); // ~649 MB
    const size_t WT_ALIGN  = (WT_BYTES + 255) & ~(size_t)255;
    const size_t BIT_BYTES = (size_t)BITWORDS * sizeof(unsigned);

    if (d_ws != nullptr && ws_size >= WT_ALIGN + BIT_BYTES) {
        float4*   WT4  = (float4*)d_ws;
        unsigned* bits = (unsigned*)((char*)d_ws + WT_ALIGN);

        ffm_clear_bits<<<(BITWORDS + 255) / 256, 256, 0, stream>>>(bits);
        ffm_mark_bits<<<(B * NS + 255) / 256, 256, 0, stream>>>(x, offsets, bits, B);

        ffm_transpose<<<TBLOCKS, TTHREADS, 0, stream>>>((const float4*)W, WT4, bits);

        int mgrid = (B < MAIN_BLOCKS) ? B : MAIN_BLOCKS;
        if (mgrid < 1) mgrid = 1;
        ffm_main<<<mgrid, MTHREADS, 0, stream>>>(x, (const float4*)WT4, fc_w, bias,
                                                 offsets, out, B);
    } else {
        ffm_kernel<<<B, 256, 0, stream>>>(x, W, fc_w, bias, offsets, out, B);
    }
}

// Round 5
// 834.794 us; speedup vs baseline: 1.2956x; 1.2956x over previous
//
#include <hip/hip_runtime.h>
#include <math.h>

#define NF 39
#define ND 13
#define KDIM 16
#define FEAT 260013
#define NPAIRS (NF * (NF + 1) / 2)    // 780 unordered pairs (i<=j)

// ---- pair-major path ----
#define G_PAIRS 5                     // pairs per block
#define PAIR_GROUPS ((NPAIRS + G_PAIRS - 1) / G_PAIRS)   // 156
#define SPLIT 4                       // sample-range splits per pair group
#define SBMAX 1024                    // max samples per block (B<=4096)
#define PTHREADS 256

// prep: xfeat[j][b] (global feature index, transposed for coalesced pair-kernel
// reads), xd[i][b] dense multipliers, clear cross accumulator.
__global__ __launch_bounds__(256) void ffm_prep(
    const float* __restrict__ x, const int* __restrict__ offsets,
    int* __restrict__ xfeat, float* __restrict__ xd,
    float* __restrict__ cross, int B)
{
    int b = blockIdx.x * 256 + threadIdx.x;
    if (b >= B) return;
    #pragma unroll
    for (int jj = 0; jj < NF; ++jj) {
        float xv = x[(size_t)b * NF + jj];
        int idx  = (jj < ND) ? 0 : (int)floorf(xv);
        xfeat[jj * B + b] = idx + offsets[jj];
        if (jj < ND) xd[jj * B + b] = xv;
    }
    cross[b] = 0.0f;
}

// Pair-major cross-term kernel. Block = (pair-group, sample-split). For each
// of its 5 pairs (i,j), all accesses hit two 640KB row-windows owned by this
// pair alone -> L2-resident after first touch; re-reads never go to HBM.
// Per sample: 8 lanes (2 quads) load W[i][f_j] / W[j][f_i] as float4s,
// dot via shfl_xor, accumulate into per-sample LDS partials; one atomicAdd
// per sample per block at flush.
__global__ __launch_bounds__(PTHREADS) void ffm_pairs(
    const float4* __restrict__ W4,    // [39 * FEAT * 4] f4
    const int*    __restrict__ xfeat, // [NF * B]
    const float*  __restrict__ xd,    // [ND * B]
    float*        __restrict__ cross, // [B]
    int B, int SB)
{
    __shared__ float sacc[SBMAX];   // per-sample partial over this block's pairs
    __shared__ int   sfi[SBMAX];    // f_i per sample (current pair)
    __shared__ int   sfj[SBMAX];
    __shared__ float smi[SBMAX];    // xm_i per sample (1.0 for sparse)
    __shared__ float smj[SBMAX];

    const int tid   = threadIdx.x;
    const int pg    = blockIdx.x / SPLIT;
    const int sp    = blockIdx.x - pg * SPLIT;
    const int sbase = sp * SB;
    const int scount = (B - sbase < SB) ? (B - sbase) : SB;
    if (scount <= 0) return;   // uniform across block

    for (int s = tid; s < SBMAX; s += PTHREADS) sacc[s] = 0.0f;

    const int slot = tid >> 3;   // 0..31: sample slot within iteration
    const int quad = (tid >> 2) & 1;

    for (int g = 0; g < G_PAIRS; ++g) {
        const int p = pg * G_PAIRS + g;
        if (p >= NPAIRS) break;

        // decode (i,j) and structural weight:
        //   i==j<38: 1 ; i<j<38: 2 ; i<j==38: 1 ; (38,38): 0
        int i = 0, base = 0;
        while (p >= base + (NF - i)) { base += NF - i; ++i; }
        const int j = i + (p - base);
        float wst;
        if (i == j)          wst = (i < NF - 1) ? 1.0f : 0.0f;
        else if (j < NF - 1) wst = 2.0f;
        else                 wst = 1.0f;

        __syncthreads();   // previous pair's LDS reads done
        for (int s = tid; s < scount; s += PTHREADS) {
            sfi[s] = xfeat[i * B + sbase + s];
            sfj[s] = xfeat[j * B + sbase + s];
            smi[s] = (i < ND) ? xd[i * B + sbase + s] : 1.0f;
            smj[s] = (j < ND) ? xd[j * B + sbase + s] : 1.0f;
        }
        __syncthreads();

        const size_t rowU = (size_t)i * FEAT;   // u = W[i][f_j]
        const size_t rowV = (size_t)j * FEAT;   // v = W[j][f_i]
        const int iters = (scount + 31) >> 5;

        #pragma unroll 4
        for (int it = 0; it < iters; ++it) {
            int  s     = (it << 5) + slot;
            bool valid = s < scount;
            int  sc    = valid ? s : 0;

            int    f    = quad ? sfi[sc] : sfj[sc];
            size_t base4 = ((quad ? rowV : rowU) + f) * 4 + (tid & 3);
            float4 v = W4[base4];

            float4 u;
            u.x = __shfl_xor(v.x, 4, 64);
            u.y = __shfl_xor(v.y, 4, 64);
            u.z = __shfl_xor(v.z, 4, 64);
            u.w = __shfl_xor(v.w, 4, 64);

            float d = v.x * u.x + v.y * u.y + v.z * u.z + v.w * u.w;
            d += __shfl_xor(d, 1, 64);
            d += __shfl_xor(d, 2, 64);   // full dot in every lane of the group

            if (valid && (tid & 7) == 0)
                sacc[sc] += wst * smi[sc] * smj[sc] * d;   // unique writer per sc
        }
    }

    __syncthreads();
    for (int s = tid; s < scount; s += PTHREADS)
        atomicAdd(&cross[sbase + s], sacc[s]);
}

// final: linear term + cross + bias -> sigmoid
__global__ __launch_bounds__(256) void ffm_final(
    const int*   __restrict__ xfeat, const float* __restrict__ cross,
    const float* __restrict__ fc_w,  const float* __restrict__ bias,
    float* __restrict__ out, int B)
{
    int b = blockIdx.x * 256 + threadIdx.x;
    if (b >= B) return;
    float lin = 0.0f;
    #pragma unroll
    for (int jj = 0; jj < NF; ++jj)
        lin += fc_w[xfeat[jj * B + b]];
    float z = lin + cross[b] + bias[0];
    out[b] = 1.0f / (1.0f + expf(-z));
}

// ---- fallback: verified round-0 kernel (native W layout, 8 lanes/pair) ----
#define PASSES ((NPAIRS + 31) / 32)
__global__ __launch_bounds__(256) void ffm_kernel(
    const float* __restrict__ x, const float* __restrict__ W,
    const float* __restrict__ fc_w, const float* __restrict__ bias,
    const int* __restrict__ offsets, float* __restrict__ out, int B)
{
    __shared__ int            sf[NF];
    __shared__ float          sxm[NF];
    __shared__ unsigned short spij[NPAIRS];
    __shared__ float          sred[4];

    const int b   = blockIdx.x;
    const int tid = threadIdx.x;

    if (tid < NF) {
        float xv = x[(size_t)b * NF + tid];
        int idx  = (tid < ND) ? 0 : (int)floorf(xv);
        sf[tid]  = idx + offsets[tid];
        sxm[tid] = (tid < ND) ? xv : 1.0f;
    }
    for (int p = tid; p < NPAIRS; p += 256) {
        int i = 0, base = 0;
        while (p >= base + (NF - i)) { base += NF - i; ++i; }
        int j = i + (p - base);
        spij[p] = (unsigned short)(i | (j << 8));
    }
    __syncthreads();

    const int slot = tid >> 3;
    const int quad = (tid >> 2) & 1;
    const int qi   = tid & 3;

    float acc = 0.0f;
    if (tid < NF) acc += fc_w[sf[tid]];

    #pragma unroll 5
    for (int pass = 0; pass < PASSES; ++pass) {
        int p  = pass * 32 + slot;
        int pc = (p < NPAIRS) ? p : (NPAIRS - 1);
        int ij = spij[pc];
        int i  = ij & 0xff;
        int j  = ij >> 8;

        float w;
        if (i == j)          w = (i < NF - 1) ? sxm[i] * sxm[i] : 0.0f;
        else if (j < NF - 1) w = 2.0f * sxm[i] * sxm[j];
        else                 w = sxm[i] * sxm[j];
        if (p >= NPAIRS) w = 0.0f;

        int row  = quad ? j : i;
        int feat = quad ? sf[i] : sf[j];
        const float4* vp = (const float4*)(W + ((size_t)row * FEAT + feat) * KDIM);
        float4 v = vp[qi];

        float4 u;
        u.x = __shfl_xor(v.x, 4, 64);
        u.y = __shfl_xor(v.y, 4, 64);
        u.z = __shfl_xor(v.z, 4, 64);
        u.w = __shfl_xor(v.w, 4, 64);

        float d = v.x * u.x + v.y * u.y + v.z * u.z + v.w * u.w;
        acc += 0.5f * w * d;
    }

    #pragma unroll
    for (int off = 32; off > 0; off >>= 1)
        acc += __shfl_down(acc, off, 64);
    if ((tid & 63) == 0) sred[tid >> 6] = acc;
    __syncthreads();

    if (tid == 0) {
        float z = sred[0] + sred[1] + sred[2] + sred[3] + bias[0];
        out[b] = 1.0f / (1.0f + expf(-z));
    }
}

extern "C" void kernel_launch(void* const* d_in, const int* in_sizes, int n_in,
                              void* d_out, int out_size, void* d_ws, size_t ws_size,
                              hipStream_t stream) {
    const float* x       = (const float*)d_in[0];
    const float* W       = (const float*)d_in[1];
    const float* fc_w    = (const float*)d_in[2];
    const float* bias    = (const float*)d_in[3];
    const int*   offsets = (const int*)d_in[4];

    float* out = (float*)d_out;
    const int B = in_sizes[0] / NF;

    // workspace layout: xfeat[NF*B] int | xd[ND*B] float | cross[B] float
    const size_t XF_BYTES = (size_t)NF * B * sizeof(int);
    const size_t XD_BYTES = (size_t)ND * B * sizeof(float);
    const size_t CR_BYTES = (size_t)B * sizeof(float);
    const size_t NEED     = XF_BYTES + XD_BYTES + CR_BYTES + 256;

    if (d_ws != nullptr && ws_size >= NEED && B <= SBMAX * SPLIT) {
        int*   xfeat = (int*)d_ws;
        float* xd    = (float*)((char*)d_ws + XF_BYTES);
        float* cross = (float*)((char*)d_ws + XF_BYTES + XD_BYTES);

        const int SB = (B + SPLIT - 1) / SPLIT;
        const int pb = (B + 255) / 256;

        ffm_prep<<<pb, 256, 0, stream>>>(x, offsets, xfeat, xd, cross, B);
        ffm_pairs<<<PAIR_GROUPS * SPLIT, PTHREADS, 0, stream>>>(
            (const float4*)W, xfeat, xd, cross, B, SB);
        ffm_final<<<pb, 256, 0, stream>>>(xfeat, cross, fc_w, bias, out, B);
    } else {
        ffm_kernel<<<B, 256, 0, stream>>>(x, W, fc_w, bias, offsets, out, B);
    }
}